// Round 12
// baseline (4953.408 us; speedup 1.0000x reference)
//
#include <hip/hip_runtime.h>
#include <cstddef>
#include <cstdint>

// Problem constants
#define TT 256
#define BB 64
#define NTAG 34
// M = TT*BB = 16384

__device__ __forceinline__ float sigf(float x) { return 1.0f / (1.0f + expf(-x)); }

// ---------------------------------------------------------------------------
// fp32 tiled GEMM v4 (r11 verified): BM=BN=128, BK=16, 256 thr, 8x8 split
// fragments (2-way LDS aliasing = free), double-buffered staging.
// ---------------------------------------------------------------------------
__global__ __launch_bounds__(256) void gemm_k(
    const float* __restrict__ Abase, const int* __restrict__ gidx,
    const float* __restrict__ W, const float* __restrict__ biasA,
    const float* __restrict__ biasB, float* __restrict__ out,
    int M, int K, int Nvalid, int xp_mode) {
  __shared__ float As[2][16][132];
  __shared__ float Bs[2][16][132];
  int tid = threadIdx.x;
  int m0 = blockIdx.x * 128;
  int n0 = blockIdx.y * 128;
  int tx = tid & 15, ty = tid >> 4;
  int srow = tid >> 2;
  int c4 = tid & 3;
  int kb = c4 * 4;

  float acc[8][8];
#pragma unroll
  for (int i = 0; i < 8; ++i)
#pragma unroll
    for (int j = 0; j < 8; ++j) acc[i][j] = 0.0f;

  const float* a0p;
  const float* a1p;
  {
    int ma = m0 + srow, mb = m0 + srow + 64;
    size_t ra = gidx ? (size_t)gidx[ma] : (size_t)ma;
    size_t rb = gidx ? (size_t)gidx[mb] : (size_t)mb;
    a0p = Abase + ra * (size_t)K + c4 * 4;
    a1p = Abase + rb * (size_t)K + c4 * 4;
  }
  int nA = n0 + srow, nB = n0 + srow + 64;
  const float* b0p = W + (size_t)nA * K + c4 * 4;
  const float* b1p = W + (size_t)nB * K + c4 * 4;
  bool v0 = nA < Nvalid, v1 = nB < Nvalid;

  {
    float4 a0 = *(const float4*)(a0p);
    float4 a1 = *(const float4*)(a1p);
    float4 b0 = v0 ? *(const float4*)(b0p) : make_float4(0, 0, 0, 0);
    float4 b1 = v1 ? *(const float4*)(b1p) : make_float4(0, 0, 0, 0);
    As[0][kb + 0][srow] = a0.x; As[0][kb + 1][srow] = a0.y;
    As[0][kb + 2][srow] = a0.z; As[0][kb + 3][srow] = a0.w;
    As[0][kb + 0][srow + 64] = a1.x; As[0][kb + 1][srow + 64] = a1.y;
    As[0][kb + 2][srow + 64] = a1.z; As[0][kb + 3][srow + 64] = a1.w;
    Bs[0][kb + 0][srow] = b0.x; Bs[0][kb + 1][srow] = b0.y;
    Bs[0][kb + 2][srow] = b0.z; Bs[0][kb + 3][srow] = b0.w;
    Bs[0][kb + 0][srow + 64] = b1.x; Bs[0][kb + 1][srow + 64] = b1.y;
    Bs[0][kb + 2][srow + 64] = b1.z; Bs[0][kb + 3][srow + 64] = b1.w;
  }
  __syncthreads();

  int cur = 0;
  for (int k0 = 0; k0 < K; k0 += 16) {
    bool more = (k0 + 16) < K;
    float4 na0, na1, nb0, nb1;
    if (more) {
      na0 = *(const float4*)(a0p + k0 + 16);
      na1 = *(const float4*)(a1p + k0 + 16);
      nb0 = v0 ? *(const float4*)(b0p + k0 + 16) : make_float4(0, 0, 0, 0);
      nb1 = v1 ? *(const float4*)(b1p + k0 + 16) : make_float4(0, 0, 0, 0);
    }
#pragma unroll
    for (int k = 0; k < 16; ++k) {
      float4 av0 = *(const float4*)&As[cur][k][ty * 4];
      float4 av1 = *(const float4*)&As[cur][k][ty * 4 + 64];
      float4 bv0 = *(const float4*)&Bs[cur][k][tx * 4];
      float4 bv1 = *(const float4*)&Bs[cur][k][tx * 4 + 64];
      float a[8] = {av0.x, av0.y, av0.z, av0.w, av1.x, av1.y, av1.z, av1.w};
      float b[8] = {bv0.x, bv0.y, bv0.z, bv0.w, bv1.x, bv1.y, bv1.z, bv1.w};
#pragma unroll
      for (int i = 0; i < 8; ++i)
#pragma unroll
        for (int j = 0; j < 8; ++j) acc[i][j] += a[i] * b[j];
    }
    if (more) {
      int nxt = cur ^ 1;
      As[nxt][kb + 0][srow] = na0.x; As[nxt][kb + 1][srow] = na0.y;
      As[nxt][kb + 2][srow] = na0.z; As[nxt][kb + 3][srow] = na0.w;
      As[nxt][kb + 0][srow + 64] = na1.x; As[nxt][kb + 1][srow + 64] = na1.y;
      As[nxt][kb + 2][srow + 64] = na1.z; As[nxt][kb + 3][srow + 64] = na1.w;
      Bs[nxt][kb + 0][srow] = nb0.x; Bs[nxt][kb + 1][srow] = nb0.y;
      Bs[nxt][kb + 2][srow] = nb0.z; Bs[nxt][kb + 3][srow] = nb0.w;
      Bs[nxt][kb + 0][srow + 64] = nb1.x; Bs[nxt][kb + 1][srow + 64] = nb1.y;
      Bs[nxt][kb + 2][srow + 64] = nb1.z; Bs[nxt][kb + 3][srow + 64] = nb1.w;
      __syncthreads();
      cur = nxt;
    }
  }

  float bsum[8];
#pragma unroll
  for (int j = 0; j < 8; ++j) {
    int n = n0 + (j < 4 ? tx * 4 + j : 64 + tx * 4 + (j - 4));
    bsum[j] = (n < Nvalid) ? (biasA[n] + (biasB ? biasB[n] : 0.0f)) : 0.0f;
  }
  if (xp_mode) {
    int dir = n0 >> 10;
    int nlo = (n0 & 1023) + tx * 4;
#pragma unroll
    for (int i = 0; i < 8; ++i) {
      int m = m0 + (i < 4 ? ty * 4 + i : 64 + ty * 4 + (i - 4));
      float* orow = out + ((size_t)dir * M + m) * 1024 + nlo;
      float4 r0 = make_float4(acc[i][0] + bsum[0], acc[i][1] + bsum[1],
                              acc[i][2] + bsum[2], acc[i][3] + bsum[3]);
      float4 r1 = make_float4(acc[i][4] + bsum[4], acc[i][5] + bsum[5],
                              acc[i][6] + bsum[6], acc[i][7] + bsum[7]);
      *(float4*)(orow) = r0;
      *(float4*)(orow + 64) = r1;
    }
  } else {
#pragma unroll
    for (int i = 0; i < 8; ++i) {
      int m = m0 + (i < 4 ? ty * 4 + i : 64 + ty * 4 + (i - 4));
#pragma unroll
      for (int j = 0; j < 8; ++j) {
        int n = n0 + (j < 4 ? tx * 4 + j : 64 + tx * 4 + (j - 4));
        if (n < Nvalid) out[(size_t)m * Nvalid + n] = acc[i][j] + bsum[j];
      }
    }
  }
}

// ---------------------------------------------------------------------------
// Register-stationary LSTM recurrence, v7: FAN-IN 4 via 2-batch groups.
// 256 blocks x 512 threads = 2 d x 32 bg(2 batches) x 4 unit-slices(64 un).
// All v3.1 protocol invariants preserved (512-thr/8-wave blocks, stamp
// packets, agent-scope RELAXED atomics, parity double-buffer, 2 barriers).
// Deltas vs v3.1: consumer waits on max-of-4 producers (was 8), 1 poll per
// thread (512 thr <-> 512 packets/group; total poll traffic halved), 3-stage
// butterfly (was 4). Thread (jl=tid>>3, kseg=tid&7) holds w[4][32] (128
// VGPR); GEMV unchanged at 256 FMA (32 k x 4 g x 2 b).
// ---------------------------------------------------------------------------
__global__ __launch_bounds__(512) void lstm_fused7(
    const float* __restrict__ xp,    // [2][M][1024]
    const float* __restrict__ whh,   // [2][1024][256]
    const int* __restrict__ lengths,
    float* __restrict__ out,         // [M][512]
    unsigned long long* hx,          // [2 slot][2 d][32 bg][512 packets]
    int T, int B) {
  __shared__ float2 hS[256];   // h[k] for 2 batches
  __shared__ float xgS[512];   // [b][g][jl] = 2 x 4 x 64
  int blk = blockIdx.x;
  int js = blk >> 6;           // 0..3 (64 units each); partners stride 64
  int inner = blk & 63;        //   -> same blk%8 -> same-XCD heuristic kept
  int d = inner >> 5;
  int bg = inner & 31;
  int tid = threadIdx.x;
  int jl = tid >> 3, kseg = tid & 7;  // jl 0..63, kseg 0..7 (32 k each)
  int j = js * 64 + jl;
  size_t M = (size_t)T * B;
  int b0 = bg * 2;

  // Stationary weights: w[g][i] = whh[d][g*256+j][kseg+8i]
  float w[4][32];
#pragma unroll
  for (int g = 0; g < 4; ++g) {
    const float* wr = whh + ((size_t)d * 1024 + g * 256 + j) * 256 + kseg;
#pragma unroll
    for (int i = 0; i < 32; ++i) w[g][i] = wr[8 * i];
  }

  int batch = b0 + (kseg & 1);
  int len = lengths[batch];
  float cst = 0.0f, hst = 0.0f;

  unsigned long long* hx_grp = hx + ((size_t)d * 32 + bg) * 512;
  const size_t slotStride = (size_t)2 * 32 * 512;  // packets per slot

  // xg loader mapping: tid -> (lb, lg, lj)
  int lb = tid >> 8, lg = (tid >> 6) & 3, lj = tid & 63;
  const float* xg_base = xp + (size_t)d * M * 1024 + (size_t)lg * 256 + js * 64 + lj;

  for (int s = 0; s < T; ++s) {
    int t = d ? (T - 1 - s) : s;
    float xv = xg_base[((size_t)t * B + b0 + lb) * 1024];
    if (s == 0) {
      ((float*)hS)[tid] = 0.0f;
    } else {
      const unsigned long long* src = hx_grp + (size_t)(s & 1) * slotStride + tid;
      unsigned int want = (unsigned int)s;
      unsigned long long p;
      int guard = 0;
      do {
        p = __hip_atomic_load(src, __ATOMIC_RELAXED, __HIP_MEMORY_SCOPE_AGENT);
      } while ((unsigned int)(p >> 32) != want && ++guard < (1 << 22));
      ((float*)hS)[tid] = __uint_as_float((unsigned int)p);
    }
    xgS[tid] = xv;
    __syncthreads();

    // GEMV over my 32 k values for 4 gates x 2 batches (256 FMA)
    float acc[4][2];
#pragma unroll
    for (int g = 0; g < 4; ++g) { acc[g][0] = 0.0f; acc[g][1] = 0.0f; }
#pragma unroll
    for (int i = 0; i < 32; ++i) {
      float2 hv = hS[kseg + 8 * i];  // 8 addrs x 8-lane broadcast, banks 2k..2k+1: conflict-free
#pragma unroll
      for (int g = 0; g < 4; ++g) {
        acc[g][0] += w[g][i] * hv.x;
        acc[g][1] += w[g][i] * hv.y;
      }
    }
    // Butterfly over the 8 kseg lanes
#pragma unroll
    for (int g = 0; g < 4; ++g)
#pragma unroll
      for (int b = 0; b < 2; ++b) {
        float v = acc[g][b];
        v += __shfl_xor(v, 1);
        v += __shfl_xor(v, 2);
        v += __shfl_xor(v, 4);
        acc[g][b] = v;
      }

    if (kseg < 2) {
      int b = kseg;
      float ig = sigf(acc[0][b] + xgS[b * 256 + 0 * 64 + jl]);
      float fg = sigf(acc[1][b] + xgS[b * 256 + 1 * 64 + jl]);
      float gg = tanhf(acc[2][b] + xgS[b * 256 + 2 * 64 + jl]);
      float og = sigf(acc[3][b] + xgS[b * 256 + 3 * 64 + jl]);
      bool m = t < len;
      float cn = fg * cst + ig * gg;
      float hn = og * tanhf(cn);
      if (m) { cst = cn; hst = hn; }
      if (s + 1 < T) {
        unsigned long long pkt =
            ((unsigned long long)(unsigned int)(s + 1) << 32) | __float_as_uint(hst);
        unsigned long long* dst = hx_grp + (size_t)((s + 1) & 1) * slotStride +
                                  (size_t)js * 128 + jl * 2 + b;
        __hip_atomic_store(dst, pkt, __ATOMIC_RELAXED, __HIP_MEMORY_SCOPE_AGENT);
      }
      out[((size_t)t * B + batch) * 512 + d * 256 + j] = m ? hst : 0.0f;
    }
    __syncthreads();
  }
}

// ---------------------------------------------------------------------------
// Viterbi v1 (verified config): one block/wave per batch element.
// ---------------------------------------------------------------------------
__global__ __launch_bounds__(64) void viterbi_k(
    const float* __restrict__ em, const int* __restrict__ lengths,
    const float* __restrict__ startT, const float* __restrict__ endT,
    const float* __restrict__ trans, int* __restrict__ hist,
    int* __restrict__ outTags, int T, int B) {
  __shared__ float tr[NTAG * NTAG];
  __shared__ float sc[NTAG];
  __shared__ float ns[NTAG];
  int b = blockIdx.x;
  int j = threadIdx.x;
  for (int i = j; i < NTAG * NTAG; i += 64) tr[i] = trans[i];
  int len = lengths[b];
  if (j < NTAG) sc[j] = startT[j] + em[(size_t)b * NTAG + j];
  __syncthreads();
  for (int t = 1; t < T; ++t) {
    if (j < NTAG) {
      float best = -3.0e38f;
      int arg = 0;
      for (int i = 0; i < NTAG; ++i) {
        float v = sc[i] + tr[i * NTAG + j];
        if (v > best) { best = v; arg = i; }
      }
      bool m = t < len;
      float e = em[((size_t)t * B + b) * NTAG + j];
      ns[j] = m ? (best + e) : sc[j];
      hist[((size_t)(t - 1) * B + b) * NTAG + j] = m ? arg : j;
    }
    __syncthreads();
    if (j < NTAG) sc[j] = ns[j];
    __syncthreads();
  }
  if (j == 0) {
    float best = -3.0e38f;
    int arg = 0;
    for (int i = 0; i < NTAG; ++i) {
      float v = sc[i] + endT[i];
      if (v > best) { best = v; arg = i; }
    }
    int tag = arg;
    outTags[(size_t)(T - 1) * B + b] = (T - 1 < len) ? tag : 0;
    for (int t = T - 2; t >= 0; --t) {
      tag = hist[((size_t)t * B + b) * NTAG + tag];
      outTags[(size_t)t * B + b] = (t < len) ? tag : 0;
    }
  }
}

extern "C" void kernel_launch(void* const* d_in, const int* in_sizes, int n_in,
                              void* d_out, int out_size, void* d_ws, size_t ws_size,
                              hipStream_t stream) {
  const int* x = (const int*)d_in[0];
  const int* lens = (const int*)d_in[1];
  const float* embed = (const float*)d_in[2];
  const float* w_ih0 = (const float*)d_in[3];
  const float* w_hh0 = (const float*)d_in[4];
  const float* b_ih0 = (const float*)d_in[5];
  const float* b_hh0 = (const float*)d_in[6];
  const float* w_ih1 = (const float*)d_in[7];
  const float* w_hh1 = (const float*)d_in[8];
  const float* b_ih1 = (const float*)d_in[9];
  const float* b_hh1 = (const float*)d_in[10];
  const float* w_lin = (const float*)d_in[11];
  const float* b_lin = (const float*)d_in[12];
  const float* startT = (const float*)d_in[13];
  const float* endT = (const float*)d_in[14];
  const float* trans = (const float*)d_in[15];
  int* outTags = (int*)d_out;

  const int T = TT, B = BB;
  const int M = T * B;

  char* ws = (char*)d_ws;
  const size_t SZ_XP = 2ull * M * 1024 * 4;
  const size_t SZ_H = (size_t)M * 512 * 4;
  const size_t SZ_EM = (size_t)M * NTAG * 4;
  const size_t SZ_HIST = (size_t)M * NTAG * 4;
  float* xp = (float*)(ws);
  float* h0 = (float*)(ws + SZ_XP);
  float* h1 = (float*)(ws + SZ_XP + SZ_H);
  float* em = (float*)(ws + SZ_XP + 2 * SZ_H);
  int* hist = (int*)(ws + SZ_XP + 2 * SZ_H + SZ_EM);
  unsigned long long* hx0 = (unsigned long long*)(ws + SZ_XP + 2 * SZ_H + SZ_EM + SZ_HIST);
  unsigned long long* hx1 = hx0 + 2ull * 2 * 32 * 512;  // 512 KB each
  // No memset needed: 0xAA poison never matches a stamp value 1..255.

  // 1. Layer-0 input projection (fused embedding gather)
  gemm_k<<<dim3(M / 128, 16), 256, 0, stream>>>(embed, x, w_ih0, b_ih0, b_hh0,
                                                xp, M, 256, 2048, 1);
  // 2. Layer-0 recurrence
  lstm_fused7<<<256, 512, 0, stream>>>(xp, w_hh0, lens, h0, hx0, T, B);

  // 3. Layer-1 input projection
  gemm_k<<<dim3(M / 128, 16), 256, 0, stream>>>(h0, nullptr, w_ih1, b_ih1, b_hh1,
                                                xp, M, 512, 2048, 1);
  // 4. Layer-1 recurrence
  lstm_fused7<<<256, 512, 0, stream>>>(xp, w_hh1, lens, h1, hx1, T, B);

  // 5. Emissions
  gemm_k<<<dim3(M / 128, 1), 256, 0, stream>>>(h1, nullptr, w_lin, b_lin, nullptr,
                                               em, M, 512, 34, 0);
  // 6. Viterbi decode
  viterbi_k<<<64, 64, 0, stream>>>(em, lens, startT, endT, trans, hist, outTags,
                                   T, B);
  (void)in_sizes; (void)n_in; (void)out_size; (void)ws_size;
}